// Round 10
// baseline (260.376 us; speedup 1.0000x reference)
//
#include <hip/hip_runtime.h>
#include <hip/hip_bf16.h>
#include <stdint.h>

#define B_ 256
#define H_ 4096
#define K_ 32768   // V*N = 1024*32

typedef __attribute__((ext_vector_type(8))) short bf16x8;
typedef __attribute__((ext_vector_type(4))) float f32x4;

__device__ __forceinline__ unsigned short f2bf(float x) {
    union { float f; unsigned int u; } c; c.f = x;
    unsigned int r = c.u + 0x7FFFu + ((c.u >> 16) & 1u);  // RNE
    return (unsigned short)(r >> 16);
}

__device__ __forceinline__ short bfc(float x) {
    __hip_bfloat16 h = __float2bfloat16(x);
    union { __hip_bfloat16 h; short s; } c; c.h = h;
    return c.s;
}

__device__ __forceinline__ float softplus_f(float x) {
    return fmaxf(x, 0.0f) + log1pf(expf(-fabsf(x)));
}

// ---------------- Kernel A: v fp32->bf16 + vt[b] = dot(v[b,:], b_v) ----------------
__global__ __launch_bounds__(256) void prep_kernel(
    const float* __restrict__ v, const float* __restrict__ bv,
    __hip_bfloat16* __restrict__ vbf, float* __restrict__ vt)
{
    const int b = blockIdx.x;
    const int t = threadIdx.x;
    const float* vr = v + (size_t)b * K_;
    unsigned short* dr = (unsigned short*)(vbf + (size_t)b * K_);
    float acc = 0.f;
    for (int i = t * 8; i < K_; i += 256 * 8) {
        float4 x0 = *(const float4*)(vr + i);
        float4 x1 = *(const float4*)(vr + i + 4);
        float4 b0 = *(const float4*)(bv + i);
        float4 b1 = *(const float4*)(bv + i + 4);
        acc += x0.x*b0.x + x0.y*b0.y + x0.z*b0.z + x0.w*b0.w
             + x1.x*b1.x + x1.y*b1.y + x1.z*b1.z + x1.w*b1.w;
        ushort4 u0, u1;
        u0.x = f2bf(x0.x); u0.y = f2bf(x0.y); u0.z = f2bf(x0.z); u0.w = f2bf(x0.w);
        u1.x = f2bf(x1.x); u1.y = f2bf(x1.y); u1.z = f2bf(x1.z); u1.w = f2bf(x1.w);
        *(ushort4*)(dr + i)     = u0;
        *(ushort4*)(dr + i + 4) = u1;
    }
    __shared__ float sm[256];
    sm[t] = acc;
    __syncthreads();
    for (int s = 128; s > 0; s >>= 1) {
        if (t < s) sm[t] += sm[t + s];
        __syncthreads();
    }
    if (t == 0) vt[b] = sm[0];
}

// ---------------- Kernel B: producer-consumer split-K GEMM, superbody staging ----------------
// BM=256 BN=64 BK=64, KS=8 (sidx == XCD id -> v slice L2-resident).
// 640 threads: 8 CONSUMER waves (8M x 1N; A bf16 global->reg dbuf; per body
// 8 ds_read_b128 + 16 MFMA, no cvt) + 2 PRODUCER waves.
//
// DRAM-locality fix: producers stage W in SUPERBODIES of 4 k-tiles (1 KB/row)
// via QUARTERS: 16 rows x 1 KB contiguous fp32 (2 waves x 8 dwordx4), through
// a 2-quarter register pipeline, cvt->bf16, swizzled ds_write into a DEPTH-8
// slot ring (8 x 8 KB bf16 = 64 KB LDS). One barrier per superbody (SB=NT/4).
//
// Producer queue at drain of quarter Q is always [Q(8), Q+1(8)] -> vmcnt(8);
// vmcnt(0) only at final quarter. Barrier after every 4th quarter-write.
// Consumer: bodies 4S..4S+3 between barriers read slots (4S+j)&7, written
// the previous interval; producer rewrites slots of superbody S-2 whose reads
// ended one barrier earlier. A-loads: private counted vmcnt(4), tail 0.

#define NCONS 8

#define LOAD_A(dst, kt) do {                                                           \
    _Pragma("unroll")                                                                  \
    for (int m_ = 0; m_ < 2; ++m_)                                                     \
      _Pragma("unroll")                                                                \
      for (int s_ = 0; s_ < 2; ++s_)                                                   \
        dst[m_*2+s_] = *(const bf16x8*)(ap[m_] + (size_t)(kt) * 64 + s_ * 32);         \
    } while (0)

#define COMPUTE(AUSE, T_) do {                                                         \
    const unsigned short* wb_ = &wtile[(T_) & 7][0];                                   \
    _Pragma("unroll")                                                                  \
    for (int s_ = 0; s_ < 2; ++s_) {                                                   \
      bf16x8 bfr[4];                                                                   \
      _Pragma("unroll")                                                                \
      for (int n_ = 0; n_ < 4; ++n_) {                                                 \
        int row_  = n_ * 16 + lr;                                                      \
        int slot_ = s_ * 4 + lg;                                                       \
        bfr[n_] = *(const bf16x8*)&wb_[row_ * 64 + ((slot_ ^ (row_ & 7)) << 3)];       \
      }                                                                                \
      _Pragma("unroll")                                                                \
      for (int m_ = 0; m_ < 2; ++m_)                                                   \
        _Pragma("unroll")                                                              \
        for (int n_ = 0; n_ < 4; ++n_)                                                 \
          acc[m_][n_] = __builtin_amdgcn_mfma_f32_16x16x32_bf16(                       \
              AUSE[m_*2+s_], bfr[n_], acc[m_][n_], 0, 0, 0);                           \
    } } while (0)

#define CBODY(T_, AUSE, ALOAD, ISSA, VMSTR) do {                                       \
    if (ISSA) LOAD_A(ALOAD, (T_) + 1);                                                 \
    asm volatile("s_waitcnt " VMSTR ::: "memory");                                     \
    COMPUTE(AUSE, T_);                                                                 \
    } while (0)

// Producer: issue quarter Q (8 x dwordx4/lane-chunked, 16 rows x 1KB contiguous)
#define PISS(dst, Q_) do {                                                             \
    const float* p_ = wlanebase + (size_t)((Q_) >> 2) * 256                            \
                                + (size_t)((Q_) & 3) * 16 * K_;                        \
    _Pragma("unroll")                                                                  \
    for (int i_ = 0; i_ < 8; ++i_)                                                     \
        dst[i_] = *(const float4*)(p_ + i_ * 4);                                       \
    } while (0)

// Producer: cvt+swizzled-write quarter Q (4 granules of 8 bf16)
#define PWRITE(src, Q_) do {                                                           \
    int base_ = ((((Q_) & ~3) + jj) & 7) * 4096 + (((Q_) & 3) * 16 + pr) * 64;        \
    _Pragma("unroll")                                                                  \
    for (int u_ = 0; u_ < 4; ++u_) {                                                   \
        float4 a_ = src[2*u_], b_ = src[2*u_+1];                                       \
        bf16x8 t_;                                                                     \
        t_[0]=bfc(a_.x); t_[1]=bfc(a_.y); t_[2]=bfc(a_.z); t_[3]=bfc(a_.w);            \
        t_[4]=bfc(b_.x); t_[5]=bfc(b_.y); t_[6]=bfc(b_.z); t_[7]=bfc(b_.w);            \
        *(bf16x8*)&wtile[0][base_ + swzofs[u_]] = t_;                                  \
    } } while (0)

#define VMW(N) asm volatile("s_waitcnt vmcnt(" #N ")" ::: "memory")
#define PBAR() asm volatile("s_waitcnt lgkmcnt(0)\n\ts_barrier" ::: "memory")

__global__ __launch_bounds__(640, 5) void gemm_kernel(
    const __hip_bfloat16* __restrict__ vbf,   // [256][32768] bf16
    const float* __restrict__ W,              // [4096][32768] fp32
    float* __restrict__ part,                 // [KS][256][4096] fp32
    int KS, int NT)                           // NT = (K_/KS)/64, mult of 4
{
    __shared__ __align__(16) unsigned short wtile[8][64 * 64];  // 8 x 8 KB bf16 ring

    const int tid  = threadIdx.x;
    const int wid  = tid >> 6;
    const int lane = tid & 63;
    const int lr   = lane & 15;
    const int lg   = lane >> 4;

    const int bid   = blockIdx.x;
    const int sidx  = bid % KS;   // k-split; == XCD id when KS==8
    const int ht    = bid / KS;
    const int h0    = ht * 64;
    const int kbase = sidx * (NT * 64);

    if (wid < NCONS) {
        // ---------------- consumer ----------------
        const __hip_bfloat16* ap[2];
        #pragma unroll
        for (int m = 0; m < 2; ++m)
            ap[m] = vbf + (size_t)(wid * 32 + m * 16 + lr) * K_ + kbase + lg * 8;

        f32x4 acc[2][4];
        #pragma unroll
        for (int m = 0; m < 2; ++m)
            #pragma unroll
            for (int n = 0; n < 4; ++n)
                acc[m][n] = (f32x4)(0.0f);

        bf16x8 aA[4], aB[4];
        LOAD_A(aA, 0);
        asm volatile("s_barrier" ::: "memory");   // prologue barrier (superbody 0 ready)

        for (int t = 0; t < NT - 4; t += 4) {
            CBODY(t,     aA, aB, true, "vmcnt(4)");
            CBODY(t + 1, aB, aA, true, "vmcnt(4)");
            CBODY(t + 2, aA, aB, true, "vmcnt(4)");
            CBODY(t + 3, aB, aA, true, "vmcnt(4)");
            asm volatile("s_barrier" ::: "memory");
        }
        CBODY(NT - 4, aA, aB, true,  "vmcnt(4)");
        CBODY(NT - 3, aB, aA, true,  "vmcnt(4)");
        CBODY(NT - 2, aA, aB, true,  "vmcnt(4)");
        CBODY(NT - 1, aB, aA, false, "vmcnt(0)");

        // Epilogue: C/D layout col=lane&15 (=h), row=(lane>>4)*4+reg (=b)
        float* pout = part + (size_t)sidx * ((size_t)B_ * H_) + h0;
        #pragma unroll
        for (int m = 0; m < 2; ++m)
            #pragma unroll
            for (int n = 0; n < 4; ++n)
                #pragma unroll
                for (int j = 0; j < 4; ++j) {
                    int brow = wid * 32 + m * 16 + lg * 4 + j;
                    int hcol = n * 16 + lr;
                    pout[(size_t)brow * H_ + hcol] = acc[m][n][j];
                }
    } else {
        // ---------------- producer ----------------
        const int pw = wid - NCONS;     // 0..1
        const int m7 = lane >> 3;       // row within 8
        const int c  = lane & 7;        // 128B chunk within the 1KB row window
        const int jj = c >> 1;          // k-tile within superbody
        const int pr = pw * 8 + m7;     // row within quarter's 16
        const float* wlanebase =
            W + (size_t)(h0 + pr) * K_ + kbase + c * 32;

        int swzofs[4];
        #pragma unroll
        for (int u = 0; u < 4; ++u)
            swzofs[u] = ((((c & 1) * 4 + u) ^ m7) << 3);

        float4 bufA[8], bufB[8];
        const int QMAX = NT;            // quarters total (= bodies)

        PISS(bufA, 0);
        PISS(bufB, 1);
        for (int Q = 0; Q < QMAX; Q += 4) {
            VMW(8); PWRITE(bufA, Q);
            if (Q + 2 < QMAX) PISS(bufA, Q + 2);
            VMW(8); PWRITE(bufB, Q + 1);
            if (Q + 3 < QMAX) PISS(bufB, Q + 3);
            VMW(8); PWRITE(bufA, Q + 2);
            if (Q + 4 < QMAX) PISS(bufA, Q + 4);
            if (Q + 4 >= QMAX) { VMW(0); } else { VMW(8); }
            PWRITE(bufB, Q + 3);
            if (Q + 5 < QMAX) PISS(bufB, Q + 5);
            PBAR();
        }
        // producers exit; consumers finish the last superbody with no barrier
    }
}

// ---------------- Kernel C: reduce splits + b_h, softplus, sum over H, + vt ----------------
__global__ __launch_bounds__(256) void reduce_kernel(
    const float* __restrict__ part, const float* __restrict__ bh,
    const float* __restrict__ vt, float* __restrict__ out, int KS)
{
    const int b = blockIdx.x;
    const int t = threadIdx.x;
    float sp = 0.f;
    const float* pb = part + (size_t)b * H_;
    for (int h = t * 4; h < H_; h += 256 * 4) {
        float4 l = *(const float4*)(bh + h);
        for (int s = 0; s < KS; ++s) {
            float4 p = *(const float4*)(pb + (size_t)s * B_ * H_ + h);
            l.x += p.x; l.y += p.y; l.z += p.z; l.w += p.w;
        }
        sp += softplus_f(l.x) + softplus_f(l.y) + softplus_f(l.z) + softplus_f(l.w);
    }
    __shared__ float sm[256];
    sm[t] = sp;
    __syncthreads();
    for (int r = 128; r > 0; r >>= 1) {
        if (t < r) sm[t] += sm[t + r];
        __syncthreads();
    }
    if (t == 0) out[b] = sm[0] + vt[b];
}

extern "C" void kernel_launch(void* const* d_in, const int* in_sizes, int n_in,
                              void* d_out, int out_size, void* d_ws, size_t ws_size,
                              hipStream_t stream)
{
    const float* v  = (const float*)d_in[0];
    const float* W  = (const float*)d_in[1];
    const float* bh = (const float*)d_in[2];
    const float* bv = (const float*)d_in[3];
    float* out = (float*)d_out;

    char* ws = (char*)d_ws;
    const size_t vbf_bytes = (size_t)B_ * K_ * sizeof(__hip_bfloat16);  // 16 MB
    __hip_bfloat16* vbf = (__hip_bfloat16*)ws;

    int KS = 8;                                   // shrink if workspace is small
    while (KS > 1 && vbf_bytes + (size_t)KS * B_ * H_ * 4 + 1024 > ws_size) KS >>= 1;

    float* part = (float*)(ws + vbf_bytes);                                  // KS*4 MB
    float* vt   = (float*)(ws + vbf_bytes + (size_t)KS * B_ * H_ * 4);       // 1 KB

    prep_kernel<<<B_, 256, 0, stream>>>(v, bv, vbf, vt);
    const int NT = (K_ / KS) / 64;                // 64 for KS=8 (mult of 4)
    gemm_kernel<<<(H_ / 64) * KS, 640, 0, stream>>>(vbf, W, part, KS, NT);
    reduce_kernel<<<B_, 256, 0, stream>>>(part, bh, vt, out, KS);
}

// Round 11
// 196.731 us; speedup vs baseline: 1.3235x; 1.3235x over previous
//
#include <hip/hip_runtime.h>
#include <hip/hip_bf16.h>
#include <stdint.h>

#define B_ 256
#define H_ 4096
#define K_ 32768   // V*N = 1024*32

typedef __attribute__((ext_vector_type(8))) short bf16x8;
typedef __attribute__((ext_vector_type(4))) float f32x4;

__device__ __forceinline__ unsigned short f2bf(float x) {
    union { float f; unsigned int u; } c; c.f = x;
    unsigned int r = c.u + 0x7FFFu + ((c.u >> 16) & 1u);  // RNE
    return (unsigned short)(r >> 16);
}

__device__ __forceinline__ short bfc(float x) {
    __hip_bfloat16 h = __float2bfloat16(x);
    union { __hip_bfloat16 h; short s; } c; c.h = h;
    return c.s;
}

__device__ __forceinline__ float softplus_f(float x) {
    return fmaxf(x, 0.0f) + log1pf(expf(-fabsf(x)));
}

// ---------------- Kernel A: v fp32->bf16 + vt[b] = dot(v[b,:], b_v) ----------------
__global__ __launch_bounds__(256) void prep_kernel(
    const float* __restrict__ v, const float* __restrict__ bv,
    __hip_bfloat16* __restrict__ vbf, float* __restrict__ vt)
{
    const int b = blockIdx.x;
    const int t = threadIdx.x;
    const float* vr = v + (size_t)b * K_;
    unsigned short* dr = (unsigned short*)(vbf + (size_t)b * K_);
    float acc = 0.f;
    for (int i = t * 8; i < K_; i += 256 * 8) {
        float4 x0 = *(const float4*)(vr + i);
        float4 x1 = *(const float4*)(vr + i + 4);
        float4 b0 = *(const float4*)(bv + i);
        float4 b1 = *(const float4*)(bv + i + 4);
        acc += x0.x*b0.x + x0.y*b0.y + x0.z*b0.z + x0.w*b0.w
             + x1.x*b1.x + x1.y*b1.y + x1.z*b1.z + x1.w*b1.w;
        ushort4 u0, u1;
        u0.x = f2bf(x0.x); u0.y = f2bf(x0.y); u0.z = f2bf(x0.z); u0.w = f2bf(x0.w);
        u1.x = f2bf(x1.x); u1.y = f2bf(x1.y); u1.z = f2bf(x1.z); u1.w = f2bf(x1.w);
        *(ushort4*)(dr + i)     = u0;
        *(ushort4*)(dr + i + 4) = u1;
    }
    __shared__ float sm[256];
    sm[t] = acc;
    __syncthreads();
    for (int s = 128; s > 0; s >>= 1) {
        if (t < s) sm[t] += sm[t + s];
        __syncthreads();
    }
    if (t == 0) vt[b] = sm[0];
}

// ---------------- Kernel B: producer-consumer split-K GEMM, BM=256 BN=128 BK=64 ----------------
// KS=16 k-splits (sidx = bid%16; XCD gets 2 x 1MB v-slices, L2-resident).
// 640 threads: 8 CONSUMER waves (each 32 M-rows x 128 N-cols; acc[2][8];
// A bf16 global->reg single-buffered in two s-halves loaded mid-body;
// per body 16 ds_read_b128 + 32 MFMA, no cvt) + 2 PRODUCER waves
// (W fp32 global->reg in two 64-row halves, 2-deep pipeline = full body of
// HBM cover, cvt->bf16, swizzled ds_write_b128 into depth-4 16KB bf16 ring).
// One s_barrier per body; both roles execute exactly NT+1 barriers.
//
// Ring: producer writes slot (t+1)&3 during consumer body t (reads slot t&3);
// slot reuse separated by 2+ barriers. Producer queue at VMW(8) is always
// [half_cur 8, half_next 8] -> drains exactly the half about to be written;
// consumer A-waits are compiler-exact (pure-A queue, straight-line code).

#define NCONS 8

#define LOAD_AS(S_, kt) do {                                                           \
    aC[(S_)]     = *(const bf16x8*)(ap[0] + (size_t)(kt) * 64 + (S_) * 32);            \
    aC[2 + (S_)] = *(const bf16x8*)(ap[1] + (size_t)(kt) * 64 + (S_) * 32);            \
    } while (0)

#define COMPUTE_S(T_, S_) do {                                                         \
    const unsigned short* wb_ = &wtile[(T_) & 3][0];                                   \
    _Pragma("unroll")                                                                  \
    for (int q_ = 0; q_ < 2; ++q_) {                                                   \
        bf16x8 bfr[4];                                                                 \
        _Pragma("unroll")                                                              \
        for (int n_ = 0; n_ < 4; ++n_) {                                               \
            int row_ = (q_ * 4 + n_) * 16 + lr;                                        \
            bfr[n_] = *(const bf16x8*)&wb_[row_ * 64 +                                 \
                        ((((S_) * 4 + lg) ^ (row_ & 7)) << 3)];                        \
        }                                                                              \
        _Pragma("unroll")                                                              \
        for (int m_ = 0; m_ < 2; ++m_)                                                 \
            _Pragma("unroll")                                                          \
            for (int n_ = 0; n_ < 4; ++n_)                                             \
                acc[m_][q_ * 4 + n_] = __builtin_amdgcn_mfma_f32_16x16x32_bf16(        \
                    aC[m_ * 2 + (S_)], bfr[n_], acc[m_][q_ * 4 + n_], 0, 0, 0);        \
    } } while (0)

#define PISS(dst, HIDX) do {                                                           \
    _Pragma("unroll")                                                                  \
    for (int j_ = 0; j_ < 4; ++j_) {                                                   \
        const float* p_ = prow[j_] + (size_t)((HIDX) & 1) * 64 * K_                    \
                                   + (size_t)((HIDX) >> 1) * 64;                       \
        dst[2*j_]   = *(const float4*)p_;                                              \
        dst[2*j_+1] = *(const float4*)(p_ + 4);                                        \
    } } while (0)

#define PWRITE(src, T_, HALF_) do {                                                    \
    _Pragma("unroll")                                                                  \
    for (int j_ = 0; j_ < 4; ++j_) {                                                   \
        int R_ = (HALF_) * 64 + j_ * 16 + pw * 8 + r8;                                 \
        float4 a_ = src[2*j_], b_ = src[2*j_+1];                                       \
        bf16x8 u_;                                                                     \
        u_[0]=bfc(a_.x); u_[1]=bfc(a_.y); u_[2]=bfc(a_.z); u_[3]=bfc(a_.w);            \
        u_[4]=bfc(b_.x); u_[5]=bfc(b_.y); u_[6]=bfc(b_.z); u_[7]=bfc(b_.w);            \
        *(bf16x8*)&wtile[(T_) & 3][R_ * 64 + swz] = u_;                                \
    } } while (0)

#define VMW(N)  asm volatile("s_waitcnt vmcnt(" #N ")" ::: "memory")
#define PBAR()  asm volatile("s_waitcnt lgkmcnt(0)\n\ts_barrier" ::: "memory")
#define CBAR()  asm volatile("s_barrier" ::: "memory")

__global__ __launch_bounds__(640, 4) void gemm_kernel(
    const __hip_bfloat16* __restrict__ vbf,   // [256][32768] bf16
    const float* __restrict__ W,              // [4096][32768] fp32
    float* __restrict__ part,                 // [KS][256][4096] fp32
    int KS, int NT)                           // NT = (K_/KS)/64, >= 3
{
    __shared__ __align__(16) unsigned short wtile[4][128 * 64];  // 4 x 16 KB bf16 ring

    const int tid  = threadIdx.x;
    const int wid  = tid >> 6;
    const int lane = tid & 63;
    const int lr   = lane & 15;
    const int lg   = lane >> 4;

    const int bid   = blockIdx.x;
    const int sidx  = bid % KS;
    const int ht    = bid / KS;
    const int h0    = ht * 128;
    const int kbase = sidx * (NT * 64);

    if (wid < NCONS) {
        // ---------------- consumer: 32 M-rows x 128 N-cols ----------------
        const __hip_bfloat16* ap[2];
        #pragma unroll
        for (int m = 0; m < 2; ++m)
            ap[m] = vbf + (size_t)(wid * 32 + m * 16 + lr) * K_ + kbase + lg * 8;

        f32x4 acc[2][8];
        #pragma unroll
        for (int m = 0; m < 2; ++m)
            #pragma unroll
            for (int n = 0; n < 8; ++n)
                acc[m][n] = (f32x4)(0.0f);

        bf16x8 aC[4];              // [m*2+s]
        LOAD_AS(0, 0);
        LOAD_AS(1, 0);
        CBAR();                    // prologue: slot 0 ready

        for (int t = 0; t < NT; ++t) {
            const bool last = (t == NT - 1);
            COMPUTE_S(t, 0);       // compiler waits exactly on aC[0],aC[2]
            if (!last) LOAD_AS(0, t + 1);   // WAR: ordered after s0 MFMAs
            COMPUTE_S(t, 1);
            if (!last) LOAD_AS(1, t + 1);
            CBAR();
        }

        // Epilogue: C/D layout col=lane&15 (=h), row=(lane>>4)*4+reg (=b)
        float* pout = part + (size_t)sidx * ((size_t)B_ * H_) + h0;
        #pragma unroll
        for (int m = 0; m < 2; ++m)
            #pragma unroll
            for (int n = 0; n < 8; ++n)
                #pragma unroll
                for (int j = 0; j < 4; ++j) {
                    int brow = wid * 32 + m * 16 + lg * 4 + j;
                    int hcol = n * 16 + lr;
                    pout[(size_t)brow * H_ + hcol] = acc[m][n][j];
                }
    } else {
        // ---------------- producer: stage [128][64] fp32 -> bf16 ring ----------------
        const int pw = wid - NCONS;   // 0..1
        const int l8 = lane & 7;      // 8-float granule within row
        const int r8 = lane >> 3;     // row-sub 0..7
        const float* prow[4];
        #pragma unroll
        for (int j = 0; j < 4; ++j)
            prow[j] = W + (size_t)(h0 + j * 16 + pw * 8 + r8) * K_ + kbase + l8 * 8;
        const int swz = ((l8 ^ r8) << 3);   // ushort offset; R&7 == r8

        float4 bufA[8], bufB[8];

        // prologue: body 0 (halves 0,1) written to slot 0; halves 2,3 in flight
        PISS(bufA, 0);
        PISS(bufB, 1);
        VMW(8);  PWRITE(bufA, 0, 0);  PISS(bufA, 2);
        VMW(8);  PWRITE(bufB, 0, 1);  PISS(bufB, 3);
        PBAR();

        for (int t = 0; t < NT - 1; ++t) {
            const bool lastp = (t == NT - 2);
            VMW(8);
            PWRITE(bufA, t + 1, 0);
            if (!lastp) PISS(bufA, 2 * (t + 2));
            if (lastp) { VMW(0); } else { VMW(8); }
            PWRITE(bufB, t + 1, 1);
            if (!lastp) PISS(bufB, 2 * (t + 2) + 1);
            PBAR();
        }
        PBAR();   // matches consumers' final body barrier
    }
}

// ---------------- Kernel C: reduce splits + b_h, softplus, sum over H, + vt ----------------
__global__ __launch_bounds__(256) void reduce_kernel(
    const float* __restrict__ part, const float* __restrict__ bh,
    const float* __restrict__ vt, float* __restrict__ out, int KS)
{
    const int b = blockIdx.x;
    const int t = threadIdx.x;
    float sp = 0.f;
    const float* pb = part + (size_t)b * H_;
    for (int h = t * 4; h < H_; h += 256 * 4) {
        float4 l = *(const float4*)(bh + h);
        for (int s = 0; s < KS; ++s) {
            float4 p = *(const float4*)(pb + (size_t)s * B_ * H_ + h);
            l.x += p.x; l.y += p.y; l.z += p.z; l.w += p.w;
        }
        sp += softplus_f(l.x) + softplus_f(l.y) + softplus_f(l.z) + softplus_f(l.w);
    }
    __shared__ float sm[256];
    sm[t] = sp;
    __syncthreads();
    for (int r = 128; r > 0; r >>= 1) {
        if (t < r) sm[t] += sm[t + r];
        __syncthreads();
    }
    if (t == 0) out[b] = sm[0] + vt[b];
}

extern "C" void kernel_launch(void* const* d_in, const int* in_sizes, int n_in,
                              void* d_out, int out_size, void* d_ws, size_t ws_size,
                              hipStream_t stream)
{
    const float* v  = (const float*)d_in[0];
    const float* W  = (const float*)d_in[1];
    const float* bh = (const float*)d_in[2];
    const float* bv = (const float*)d_in[3];
    float* out = (float*)d_out;

    char* ws = (char*)d_ws;
    const size_t vbf_bytes = (size_t)B_ * K_ * sizeof(__hip_bfloat16);  // 16 MB
    __hip_bfloat16* vbf = (__hip_bfloat16*)ws;

    int KS = 16;                                  // shrink if workspace is small
    while (KS > 1 && vbf_bytes + (size_t)KS * B_ * H_ * 4 + 1024 > ws_size) KS >>= 1;

    float* part = (float*)(ws + vbf_bytes);                                  // KS*4 MB
    float* vt   = (float*)(ws + vbf_bytes + (size_t)KS * B_ * H_ * 4);       // 1 KB

    prep_kernel<<<B_, 256, 0, stream>>>(v, bv, vbf, vt);
    const int NT = (K_ / KS) / 64;                // 32 for KS=16
    gemm_kernel<<<(H_ / 128) * KS, 640, 0, stream>>>(vbf, W, part, KS, NT);
    reduce_kernel<<<B_, 256, 0, stream>>>(part, bh, vt, out, KS);
}